// Round 2
// baseline (307.749 us; speedup 1.0000x reference)
//
#include <hip/hip_runtime.h>
#include <hip/hip_fp16.h>

typedef _Float16 half8 __attribute__((ext_vector_type(8)));
typedef float floatx4 __attribute__((ext_vector_type(4)));

#define OSH 13            // src-octile shift for csr ordering (locality in gather)

// ---------------- QR: 3x3 Householder, LAPACK sgeqrf/sorgqr convention ----------------
__device__ inline void qr3_q(const double A[3][3], double Q[3][3]){
  double a[3][3];
#pragma unroll
  for (int r = 0; r < 3; r++)
#pragma unroll
    for (int c = 0; c < 3; c++) a[r][c] = A[r][c];

  double v1[3] = {1.0, 0.0, 0.0};
  double tau1 = 0.0;
  {
    double xn2 = a[1][0]*a[1][0] + a[2][0]*a[2][0];
    if (xn2 != 0.0){
      double alpha = a[0][0];
      double beta = -copysign(sqrt(alpha*alpha + xn2), alpha);
      tau1 = (beta - alpha) / beta;
      double inv = 1.0 / (alpha - beta);
      v1[1] = a[1][0] * inv;
      v1[2] = a[2][0] * inv;
#pragma unroll
      for (int c = 1; c < 3; c++){
        double w = a[0][c] + v1[1]*a[1][c] + v1[2]*a[2][c];
        double tw = tau1 * w;
        a[0][c] -= tw;
        a[1][c] -= tw * v1[1];
        a[2][c] -= tw * v1[2];
      }
    }
  }
  double tau2 = 0.0, v2 = 0.0;
  {
    double x2 = a[2][1];
    if (x2 != 0.0){
      double alpha = a[1][1];
      double beta = -copysign(sqrt(alpha*alpha + x2*x2), alpha);
      tau2 = (beta - alpha) / beta;
      v2 = x2 / (alpha - beta);
    }
  }
  double M[3][3] = {{1.0, 0.0, 0.0},
                    {0.0, 1.0 - tau2, -tau2*v2},
                    {0.0, -tau2*v2, 1.0 - tau2*v2*v2}};
#pragma unroll
  for (int c = 0; c < 3; c++){
    double w = v1[0]*M[0][c] + v1[1]*M[1][c] + v1[2]*M[2][c];
#pragma unroll
    for (int r = 0; r < 3; r++)
      Q[r][c] = M[r][c] - tau1 * v1[r] * w;
  }
}

// ---------------- SE(3) per-node epilogue from a local ds[13] ----------------
__device__ inline void se3_node_ds(int n, const float ds[13],
                                   const float* __restrict__ bc, const float* __restrict__ bR,
                                   const float* __restrict__ bt, const float* __restrict__ pos_in,
                                   float* __restrict__ pos_o, float* __restrict__ R_o,
                                   float* __restrict__ t_o, int layer){
  double A[3][3], Q[3][3];
#pragma unroll
  for (int r = 0; r < 3; r++)
#pragma unroll
    for (int c = 0; c < 3; c++)
      A[r][c] = (double)ds[1 + r*3 + c] + (double)bR[r*3 + c];
  qr3_q(A, Q);

  double pd = (double)ds[0] + (double)bc[0];
#pragma unroll
  for (int c = 0; c < 3; c++){
    double base = (layer == 0) ? (double)pos_in[n*3 + c] : (double)pos_o[n*3 + c];
    pos_o[n*3 + c] = (float)(base + pd);
  }

  if (layer == 0){
#pragma unroll
    for (int r = 0; r < 3; r++)
#pragma unroll
      for (int c = 0; c < 3; c++)
        R_o[n*9 + r*3 + c] = (float)Q[r][c];
  } else {
    double Rold[3][3];
#pragma unroll
    for (int r = 0; r < 3; r++)
#pragma unroll
      for (int c = 0; c < 3; c++)
        Rold[r][c] = (double)R_o[n*9 + r*3 + c];
#pragma unroll
    for (int r = 0; r < 3; r++)
#pragma unroll
      for (int c = 0; c < 3; c++){
        double s = Q[r][0]*Rold[0][c] + Q[r][1]*Rold[1][c] + Q[r][2]*Rold[2][c];
        R_o[n*9 + r*3 + c] = (float)s;
      }
  }
#pragma unroll
  for (int c = 0; c < 3; c++){
    double base = (layer == 0) ? 0.0 : (double)t_o[n*3 + c];
    t_o[n*3 + c] = (float)(base + (double)ds[10 + c] + (double)bt[c]);
  }
}

// ---------------- weight prep (+ cursor zero-init, fused) ----------------
// wTx: 4 slots x 128 cols x 128 k (main W, B-frag layout [col][k])
// wHd: 3 slots x 16 cols x 128 k (head W of layer l in slot l; cols 13-15 zero)
__global__ void k_prep_w(const float* __restrict__ Wl, const float* __restrict__ Wf,
                         const float* __restrict__ Wc, const float* __restrict__ WR,
                         const float* __restrict__ Wt, _Float16* __restrict__ wTx,
                         _Float16* __restrict__ wHd,
                         int* __restrict__ cursor, int nbuck){
  int t = blockIdx.x*256 + threadIdx.x;
  if (blockIdx.x == 0 && threadIdx.x < nbuck) cursor[threadIdx.x] = 0;
  if (t < 4*128*128){
    int l = t >> 14;
    int n = (t >> 7) & 127;
    int k = t & 127;
    const float* W = (l < 3) ? (Wl + (size_t)l*16384) : Wf;
    wTx[t] = (_Float16)W[k*128 + n];
  } else if (t < 4*128*128 + 3*16*128){
    int u = t - 4*128*128;
    int l = u >> 11;              // 16*128 = 2048 per slot
    int r = u & 2047;
    int n = r >> 7;
    int k = r & 127;
    float v = 0.f;
    if (n == 0)      v = Wc[(size_t)l*128 + k];
    else if (n < 10) v = WR[(size_t)l*1152 + k*9 + (n-1)];
    else if (n < 13) v = Wt[(size_t)l*384 + k*3 + (n-10)];
    wHd[u] = (_Float16)v;
  }
}

// ---------------- x fp32 -> fp16 (row N zeroed for csr padding) ----------------
__launch_bounds__(256)
__global__ void k_cvt(const float* __restrict__ x, _Float16* __restrict__ o, int N){
  int c = blockIdx.x*256 + threadIdx.x;       // half8 chunk id
  if (c >= (N+1)*16) return;
  int n = c >> 4;
  half8 h = {};
  if (n < N){
    const float* p = x + (size_t)c*8;
    float4 f0 = *(const float4*)p;
    float4 f1 = *(const float4*)(p + 4);
    h[0]=(_Float16)f0.x; h[1]=(_Float16)f0.y; h[2]=(_Float16)f0.z; h[3]=(_Float16)f0.w;
    h[4]=(_Float16)f1.x; h[5]=(_Float16)f1.y; h[6]=(_Float16)f1.z; h[7]=(_Float16)f1.w;
  }
  *(half8*)(o + (size_t)c*8) = h;
}

// ---------------- pass 1: bin edges into 512-node buckets ----------------
__launch_bounds__(256)
__global__ void k_bin(const int* __restrict__ src, const int* __restrict__ dst,
                      int E, int nbuck, int capB,
                      int* __restrict__ cursor, int* __restrict__ binned){
  __shared__ int cnt[128];
  __shared__ int segbase[128];
  const int tid = threadIdx.x;
  for (int t = tid; t < nbuck; t += 256) cnt[t] = 0;
  __syncthreads();
  const int e0 = blockIdx.x*4096 + tid;
  int pk[16], bk[16];
#pragma unroll
  for (int j = 0; j < 16; j++){
    int e = e0 + j*256;
    if (e < E){
      int d = dst[e], s = src[e];
      bk[j] = d >> 9;
      pk[j] = (s << 9) | (d & 511);
      atomicAdd(&cnt[bk[j]], 1);
    } else bk[j] = -1;
  }
  __syncthreads();
  for (int t = tid; t < nbuck; t += 256){
    int c = cnt[t];
    if (c > 0) segbase[t] = t*capB + atomicAdd(&cursor[t], c);
    cnt[t] = 0;
  }
  __syncthreads();
#pragma unroll
  for (int j = 0; j < 16; j++){
    if (bk[j] >= 0){
      int ord = atomicAdd(&cnt[bk[j]], 1);
      binned[segbase[bk[j]] + ord] = pk[j];
    }
  }
}

// ---------------- pass 2: per-bucket CSR, src-octile-ordered neighbor lists ----------------
// sd[n] = (csr_start, (true_deg << 16) | padded_deg)
__launch_bounds__(256)
__global__ void k_build(const int* __restrict__ binned, const int* __restrict__ cursor,
                        int N, int capB, int capC,
                        int2* __restrict__ sd, int* __restrict__ csr){
  __shared__ int deg2[512*8];
  __shared__ int lst2[512*8];
  __shared__ int cnt2[512*8];
  __shared__ int scn[256];
  const int b = blockIdx.x, tid = threadIdx.x;
  for (int t = tid; t < 512*8; t += 256){ deg2[t] = 0; cnt2[t] = 0; }
  __syncthreads();
  const int nE = cursor[b];
  const int gbase = b*capB;
  for (int i = tid; i < nE; i += 256){
    int v = binned[gbase + i];
    int o = v >> (9 + OSH);
    if (o > 7) o = 7;
    atomicAdd(&deg2[((v & 511) << 3) + o], 1);
  }
  __syncthreads();
  int d0 = 0, d1 = 0;
#pragma unroll
  for (int o = 0; o < 8; o++){ d0 += deg2[((2*tid) << 3) + o]; d1 += deg2[((2*tid+1) << 3) + o]; }
  const int p0 = (d0+7)&~7, p1 = (d1+7)&~7;
  scn[tid] = p0 + p1;
  __syncthreads();
#pragma unroll
  for (int off = 1; off < 256; off <<= 1){
    int add = (tid >= off) ? scn[tid-off] : 0;
    __syncthreads();
    scn[tid] += add;
    __syncthreads();
  }
  const int ex = scn[tid] - (p0 + p1);
  const int csrb = b*capC;
  {
    int off0 = ex;
#pragma unroll
    for (int o = 0; o < 8; o++){ lst2[((2*tid) << 3) + o] = off0; off0 += deg2[((2*tid) << 3) + o]; }
    int off1 = ex + p0;
#pragma unroll
    for (int o = 0; o < 8; o++){ lst2[((2*tid+1) << 3) + o] = off1; off1 += deg2[((2*tid+1) << 3) + o]; }
  }
  const int n0 = b*512 + 2*tid, n1 = n0 + 1;
  if (n0 < N) sd[n0] = make_int2(csrb + ex, (d0 << 16) | p0);
  if (n1 < N) sd[n1] = make_int2(csrb + ex + p0, (d1 << 16) | p1);
  __syncthreads();
  for (int i = tid; i < nE; i += 256){
    int v = binned[gbase + i];
    int dl = v & 511, s = v >> 9;
    int o = s >> OSH; if (o > 7) o = 7;
    int ord = atomicAdd(&cnt2[(dl << 3) + o], 1);
    csr[csrb + lst2[(dl << 3) + o] + ord] = s;
  }
  for (int j = d0; j < p0; j++) csr[csrb + ex + j] = N;
  for (int j = d1; j < p1; j++) csr[csrb + ex + p0 + j] = N;
}

// ---------------- fused layer kernel: out_l = (A x_l) W_l + deg*b, heads + SE(3) ----------
// Per block: 32 nodes (doubled grid vs R1 for latency-hiding occupancy in the gather).
// Phase 1: each wave gather-aggregates 8 rows of A*x into LDS (fp16).
// Phase 2: 32x128x128 MFMA GEMM (A from LDS, B=wTx), deg-scaled bias, stage out to LDS.
// Phase 3: coalesced global store of out (+ zero row N) and 32x16x128 head MFMA from LDS.
// Phase 4: SE(3) epilogue (threads 0-31) for this layer.
__launch_bounds__(256)
__global__ void k_fused(const _Float16* __restrict__ Xin,     // (N+1) rows fp16
                        const _Float16* __restrict__ Wmain,   // 128x128 [col][k]
                        const _Float16* __restrict__ Whd,     // 16x128  [col][k]
                        const float* __restrict__ bias,       // bl[layer] (128)
                        const int* __restrict__ csr, const int2* __restrict__ sd,
                        _Float16* __restrict__ Out,           // (N+1) rows fp16
                        int N, int layer,
                        const float* __restrict__ bc, const float* __restrict__ bR,
                        const float* __restrict__ bt, const float* __restrict__ pos_in,
                        float* __restrict__ pos_o, float* __restrict__ R_o,
                        float* __restrict__ t_o){
  __shared__ __align__(16) _Float16 lg[32][136];   // gather tile, reused for out staging
  __shared__ __align__(16) float lheads[32*16];
  __shared__ float ldeg[32];

  const int tid  = threadIdx.x;
  const int wave = tid >> 6;
  const int lane = tid & 63;
  const int quad = lane >> 4;
  const int l16  = lane & 15;
  const int rbase0 = blockIdx.x*32;

  // ---- phase 1: gather-aggregate (wave w -> local rows w*8 .. w*8+7) ----
  {
    const int nbase = rbase0 + wave*8;
    int nn = nbase + (lane & 7);
    int2 sv = (nn < N) ? sd[nn] : make_int2(0, 0);
    const unsigned int* Xu = (const unsigned int*)Xin;
    for (int i = 0; i < 8; i++){
      int s0    = __builtin_amdgcn_readlane(sv.x, i);
      int dpack = __builtin_amdgcn_readlane(sv.y, i);
      int degp  = dpack & 0xffff;
      if (lane == 0) ldeg[wave*8 + i] = (float)(dpack >> 16);
      float acc0 = 0.f, acc1 = 0.f;
      for (int base = 0; base < degp; base += 64){
        int myidx = csr[s0 + base + lane];          // one coalesced load covers 64 edges
        int m = degp - base; m = (m < 64) ? m : 64; // multiple of 8
        for (int k = 0; k < m; k += 8){
          unsigned int v[8];
#pragma unroll
          for (int j = 0; j < 8; j++){
            int idx = __builtin_amdgcn_readlane(myidx, k + j);   // SGPR row index
            v[j] = Xu[(size_t)idx*64 + lane];
          }
#pragma unroll
          for (int j = 0; j < 8; j++){
            float2 f = __half22float2(*(__half2*)&v[j]);
            acc0 += f.x; acc1 += f.y;
          }
        }
      }
      __half2 ho = __floats2half2_rn(acc0, acc1);
      ((unsigned int*)&lg[wave*8 + i][0])[lane] = *(unsigned int*)&ho;
    }
  }
  __syncthreads();

  // ---- phase 2: MFMA GEMM. wave w: row-tile (w&1), col-quarter (w>>1) ----
  const int rt = wave & 1;          // rows rt*16 .. rt*16+15
  const int cq = wave >> 1;         // cols cq*64 .. cq*64+63 (4 col-tiles)
  half8 af[4];
#pragma unroll
  for (int kc = 0; kc < 4; kc++)
    af[kc] = *(const half8*)&lg[rt*16 + l16][kc*32 + quad*8];
  __syncthreads();   // all lg reads done before out staging overwrites it

  floatx4 acc[4] = {};
#pragma unroll
  for (int kc = 0; kc < 4; kc++)
#pragma unroll
    for (int ct = 0; ct < 4; ct++){
      half8 bf = *(const half8*)(Wmain + (size_t)((cq*4 + ct)*16 + l16)*128 + kc*32 + quad*8);
      acc[ct] = __builtin_amdgcn_mfma_f32_16x16x32_f16(af[kc], bf, acc[ct], 0, 0, 0);
    }

  // ---- stage out to LDS (deg-scaled bias: reference sums (x W + b) over neighbors) ----
  {
    float dgv[4];
#pragma unroll
    for (int reg = 0; reg < 4; reg++)
      dgv[reg] = ldeg[rt*16 + quad*4 + reg];
#pragma unroll
    for (int ct = 0; ct < 4; ct++){
      int col = (cq*4 + ct)*16 + l16;
      float b = bias[col];
#pragma unroll
      for (int reg = 0; reg < 4; reg++){
        int rl = rt*16 + quad*4 + reg;
        lg[rl][col] = (_Float16)(acc[ct][reg] + b*dgv[reg]);
      }
    }
  }
  __syncthreads();

  // ---- phase 3a: coalesced global store (half8 chunks), zero row N for csr padding ----
#pragma unroll
  for (int i = 0; i < 2; i++){
    int idx8 = i*256 + tid;            // 512 half8 chunks
    int row = idx8 >> 4, c8 = idx8 & 15;
    int gr = rbase0 + row;
    if (gr < N){
      *(half8*)(Out + (size_t)gr*128 + c8*8) = *(const half8*)&lg[row][c8*8];
    } else if (gr == N){
      half8 z = {};
      *(half8*)(Out + (size_t)gr*128 + c8*8) = z;
    }
  }

  // ---- phase 3b: head GEMM out_l @ Whd (waves 0,1 -> row-tiles 0,1) ----
  if (wave < 2){
    floatx4 hacc = {};
#pragma unroll
    for (int kc = 0; kc < 4; kc++){
      half8 ha = *(const half8*)&lg[wave*16 + l16][kc*32 + quad*8];
      half8 bf = *(const half8*)(Whd + (size_t)l16*128 + kc*32 + quad*8);
      hacc = __builtin_amdgcn_mfma_f32_16x16x32_f16(ha, bf, hacc, 0, 0, 0);
    }
#pragma unroll
    for (int reg = 0; reg < 4; reg++)
      lheads[(wave*16 + quad*4 + reg)*16 + l16] = hacc[reg];
  }
  __syncthreads();

  // ---- phase 4: SE(3) epilogue for this layer ----
  if (tid < 32){
    int n = rbase0 + tid;
    if (n < N){
      float ds[13];
#pragma unroll
      for (int c = 0; c < 13; c++) ds[c] = lheads[tid*16 + c];
      se3_node_ds(n, ds, bc, bR, bt, pos_in, pos_o, R_o, t_o, layer);
    }
  }
}

// ---------------- final GEMM: z = out_2 @ Wf + bf (fp32 out, no gather/heads) ----------
__launch_bounds__(256)
__global__ void k_final(const _Float16* __restrict__ X, const _Float16* __restrict__ Wmain,
                        const float* __restrict__ bias, float* __restrict__ Z, int M){
  __shared__ __align__(16) float lf[64][128];
  const int tid  = threadIdx.x;
  const int wave = tid >> 6;
  const int lane = tid & 63;
  const int quad = lane >> 4;
  const int l16  = lane & 15;
  const int rbase0 = blockIdx.x*64;
  const int rbase  = rbase0 + (wave & 1)*32;
  const int cthi = wave >> 1;

  half8 af[4][2];
#pragma unroll
  for (int kc = 0; kc < 4; kc++)
#pragma unroll
    for (int rt = 0; rt < 2; rt++){
      int r = rbase + rt*16 + l16;
      r = (r < M) ? r : (M - 1);
      af[kc][rt] = *(const half8*)(X + (size_t)r*128 + kc*32 + quad*8);
    }

  floatx4 acc[2][4] = {};
#pragma unroll
  for (int kc = 0; kc < 4; kc++)
#pragma unroll
    for (int ct = 0; ct < 4; ct++){
      half8 bf = *(const half8*)(Wmain + (size_t)((cthi*4 + ct)*16 + l16)*128 + kc*32 + quad*8);
      acc[0][ct] = __builtin_amdgcn_mfma_f32_16x16x32_f16(af[kc][0], bf, acc[0][ct], 0, 0, 0);
      acc[1][ct] = __builtin_amdgcn_mfma_f32_16x16x32_f16(af[kc][1], bf, acc[1][ct], 0, 0, 0);
    }

#pragma unroll
  for (int rt = 0; rt < 2; rt++)
#pragma unroll
    for (int ct = 0; ct < 4; ct++){
      int col = (cthi*4 + ct)*16 + l16;
      float b = bias[col];
#pragma unroll
      for (int reg = 0; reg < 4; reg++){
        int rl = (wave & 1)*32 + rt*16 + quad*4 + reg;
        lf[rl][col] = acc[rt][ct][reg] + b;
      }
    }
  __syncthreads();

#pragma unroll
  for (int i = 0; i < 8; i++){
    int idx4 = i*256 + tid;            // 2048 float4 chunks
    int row = idx4 >> 5, c4 = idx4 & 31;
    int gr = rbase0 + row;
    if (gr < M)
      *(float4*)(Z + (size_t)gr*128 + c4*4) = *(const float4*)&lf[row][c4*4];
  }
}

extern "C" void kernel_launch(void* const* d_in, const int* in_sizes, int n_in,
                              void* d_out, int out_size, void* d_ws, size_t ws_size,
                              hipStream_t stream){
  const float* x0  = (const float*)d_in[0];
  const float* pos = (const float*)d_in[1];
  const int*   ei  = (const int*)d_in[2];
  const float* Wl  = (const float*)d_in[3];
  const float* bl  = (const float*)d_in[4];
  const float* Wc  = (const float*)d_in[5];
  const float* bc  = (const float*)d_in[6];
  const float* WR  = (const float*)d_in[7];
  const float* bR  = (const float*)d_in[8];
  const float* Wt  = (const float*)d_in[9];
  const float* bt  = (const float*)d_in[10];
  const float* Wf  = (const float*)d_in[11];
  const float* bf  = (const float*)d_in[12];

  const int N = in_sizes[0] / 128;
  const int E = in_sizes[2] / 2;
  const int* srcp = ei;
  const int* dstp = ei + E;

  float* z_out = (float*)d_out;
  float* pos_o = z_out + (size_t)N*128;
  float* R_o   = pos_o + (size_t)N*3;
  float* t_o   = R_o   + (size_t)N*9;

  const int nbuck = (N + 511) >> 9;
  const int capB  = (((E + nbuck - 1)/nbuck)*5/4 + 256 + 63) & ~63;
  const int capC  = capB + 512*7;

  char* ws = (char*)d_ws;
  size_t off = 0;
  auto alloc = [&](size_t bytes)->char*{
    char* p = ws + off; off += (bytes + 511) & ~(size_t)511; return p;
  };
  _Float16* bufA = (_Float16*)alloc((size_t)(N+1)*128*2);   // x16 / out1
  _Float16* bufB = (_Float16*)alloc((size_t)(N+1)*128*2);   // out0 / out2
  _Float16* wTx  = (_Float16*)alloc((size_t)4*128*128*2);
  _Float16* wHd  = (_Float16*)alloc((size_t)3*16*128*2);
  int2*  sd     = (int2*) alloc((size_t)N*8);
  int*   cursor = (int*)  alloc((size_t)nbuck*4);
  int*   binned = (int*)  alloc((size_t)nbuck*capB*4);
  int*   csr    = (int*)  alloc((size_t)nbuck*capC*4);

  const int prep_total = 4*128*128 + 3*16*128;
  k_prep_w<<<dim3((prep_total + 255)/256), dim3(256), 0, stream>>>(
      Wl, Wf, Wc, WR, Wt, wTx, wHd, cursor, nbuck);
  k_bin   <<<dim3((E + 4095)/4096), dim3(256), 0, stream>>>(srcp, dstp, E, nbuck, capB, cursor, binned);
  k_build <<<dim3(nbuck), dim3(256), 0, stream>>>(binned, cursor, N, capB, capC, sd, csr);
  k_cvt   <<<dim3(((N+1)*16 + 255)/256), dim3(256), 0, stream>>>(x0, bufA, N);

  const int fused_blocks = (N + 32) >> 5;   // 32 rows/block; covers zero-pad row N
  const int final_blocks = (N + 63) >> 6;

  const _Float16* xin = bufA;
  _Float16* xout = bufB;
  for (int layer = 0; layer < 3; layer++){
    k_fused<<<dim3(fused_blocks), dim3(256), 0, stream>>>(
        xin, wTx + (size_t)layer*16384, wHd + (size_t)layer*2048, bl + (size_t)layer*128,
        csr, sd, xout, N, layer,
        bc + layer, bR + (size_t)layer*9, bt + (size_t)layer*3,
        pos, pos_o, R_o, t_o);
    const _Float16* tmp = xin; xin = xout; xout = (_Float16*)tmp;
  }
  // after 3 swaps: xin = out_2
  k_final<<<dim3(final_blocks), dim3(256), 0, stream>>>(
      xin, wTx + (size_t)3*16384, bf, z_out, N);
}

// Round 3
// 294.839 us; speedup vs baseline: 1.0438x; 1.0438x over previous
//
#include <hip/hip_runtime.h>
#include <hip/hip_fp16.h>

typedef _Float16 half8 __attribute__((ext_vector_type(8)));
typedef float floatx4 __attribute__((ext_vector_type(4)));

#define OSH 13            // src-octile shift for csr ordering (locality in gather)

// ---------------- QR: 3x3 Householder, LAPACK sgeqrf/sorgqr convention ----------------
__device__ inline void qr3_q(const double A[3][3], double Q[3][3]){
  double a[3][3];
#pragma unroll
  for (int r = 0; r < 3; r++)
#pragma unroll
    for (int c = 0; c < 3; c++) a[r][c] = A[r][c];

  double v1[3] = {1.0, 0.0, 0.0};
  double tau1 = 0.0;
  {
    double xn2 = a[1][0]*a[1][0] + a[2][0]*a[2][0];
    if (xn2 != 0.0){
      double alpha = a[0][0];
      double beta = -copysign(sqrt(alpha*alpha + xn2), alpha);
      tau1 = (beta - alpha) / beta;
      double inv = 1.0 / (alpha - beta);
      v1[1] = a[1][0] * inv;
      v1[2] = a[2][0] * inv;
#pragma unroll
      for (int c = 1; c < 3; c++){
        double w = a[0][c] + v1[1]*a[1][c] + v1[2]*a[2][c];
        double tw = tau1 * w;
        a[0][c] -= tw;
        a[1][c] -= tw * v1[1];
        a[2][c] -= tw * v1[2];
      }
    }
  }
  double tau2 = 0.0, v2 = 0.0;
  {
    double x2 = a[2][1];
    if (x2 != 0.0){
      double alpha = a[1][1];
      double beta = -copysign(sqrt(alpha*alpha + x2*x2), alpha);
      tau2 = (beta - alpha) / beta;
      v2 = x2 / (alpha - beta);
    }
  }
  double M[3][3] = {{1.0, 0.0, 0.0},
                    {0.0, 1.0 - tau2, -tau2*v2},
                    {0.0, -tau2*v2, 1.0 - tau2*v2*v2}};
#pragma unroll
  for (int c = 0; c < 3; c++){
    double w = v1[0]*M[0][c] + v1[1]*M[1][c] + v1[2]*M[2][c];
#pragma unroll
    for (int r = 0; r < 3; r++)
      Q[r][c] = M[r][c] - tau1 * v1[r] * w;
  }
}

// ---------------- SE(3) per-node epilogue from a local ds[13] ----------------
__device__ inline void se3_node_ds(int n, const float ds[13],
                                   const float* __restrict__ bc, const float* __restrict__ bR,
                                   const float* __restrict__ bt, const float* __restrict__ pos_in,
                                   float* __restrict__ pos_o, float* __restrict__ R_o,
                                   float* __restrict__ t_o, int layer){
  double A[3][3], Q[3][3];
#pragma unroll
  for (int r = 0; r < 3; r++)
#pragma unroll
    for (int c = 0; c < 3; c++)
      A[r][c] = (double)ds[1 + r*3 + c] + (double)bR[r*3 + c];
  qr3_q(A, Q);

  double pd = (double)ds[0] + (double)bc[0];
#pragma unroll
  for (int c = 0; c < 3; c++){
    double base = (layer == 0) ? (double)pos_in[n*3 + c] : (double)pos_o[n*3 + c];
    pos_o[n*3 + c] = (float)(base + pd);
  }

  if (layer == 0){
#pragma unroll
    for (int r = 0; r < 3; r++)
#pragma unroll
      for (int c = 0; c < 3; c++)
        R_o[n*9 + r*3 + c] = (float)Q[r][c];
  } else {
    double Rold[3][3];
#pragma unroll
    for (int r = 0; r < 3; r++)
#pragma unroll
      for (int c = 0; c < 3; c++)
        Rold[r][c] = (double)R_o[n*9 + r*3 + c];
#pragma unroll
    for (int r = 0; r < 3; r++)
#pragma unroll
      for (int c = 0; c < 3; c++){
        double s = Q[r][0]*Rold[0][c] + Q[r][1]*Rold[1][c] + Q[r][2]*Rold[2][c];
        R_o[n*9 + r*3 + c] = (float)s;
      }
  }
#pragma unroll
  for (int c = 0; c < 3; c++){
    double base = (layer == 0) ? 0.0 : (double)t_o[n*3 + c];
    t_o[n*3 + c] = (float)(base + (double)ds[10 + c] + (double)bt[c]);
  }
}

// ---------------- weight prep (+ cursor zero-init, fused) ----------------
// wTx: 4 slots x 128 cols x 128 k (main W, B-frag layout [col][k])
// wHd: 3 slots x 16 cols x 128 k (head W of layer l in slot l; cols 13-15 zero)
__global__ void k_prep_w(const float* __restrict__ Wl, const float* __restrict__ Wf,
                         const float* __restrict__ Wc, const float* __restrict__ WR,
                         const float* __restrict__ Wt, _Float16* __restrict__ wTx,
                         _Float16* __restrict__ wHd,
                         int* __restrict__ cursor, int nbuck){
  int t = blockIdx.x*256 + threadIdx.x;
  if (blockIdx.x == 0 && threadIdx.x < nbuck) cursor[threadIdx.x] = 0;
  if (t < 4*128*128){
    int l = t >> 14;
    int n = (t >> 7) & 127;
    int k = t & 127;
    const float* W = (l < 3) ? (Wl + (size_t)l*16384) : Wf;
    wTx[t] = (_Float16)W[k*128 + n];
  } else if (t < 4*128*128 + 3*16*128){
    int u = t - 4*128*128;
    int l = u >> 11;              // 16*128 = 2048 per slot
    int r = u & 2047;
    int n = r >> 7;
    int k = r & 127;
    float v = 0.f;
    if (n == 0)      v = Wc[(size_t)l*128 + k];
    else if (n < 10) v = WR[(size_t)l*1152 + k*9 + (n-1)];
    else if (n < 13) v = Wt[(size_t)l*384 + k*3 + (n-10)];
    wHd[u] = (_Float16)v;
  }
}

// ---------------- x fp32 -> fp16 (row N zeroed for csr padding) ----------------
__launch_bounds__(256)
__global__ void k_cvt(const float* __restrict__ x, _Float16* __restrict__ o, int N){
  int c = blockIdx.x*256 + threadIdx.x;       // half8 chunk id
  if (c >= (N+1)*16) return;
  int n = c >> 4;
  half8 h = {};
  if (n < N){
    const float* p = x + (size_t)c*8;
    float4 f0 = *(const float4*)p;
    float4 f1 = *(const float4*)(p + 4);
    h[0]=(_Float16)f0.x; h[1]=(_Float16)f0.y; h[2]=(_Float16)f0.z; h[3]=(_Float16)f0.w;
    h[4]=(_Float16)f1.x; h[5]=(_Float16)f1.y; h[6]=(_Float16)f1.z; h[7]=(_Float16)f1.w;
  }
  *(half8*)(o + (size_t)c*8) = h;
}

// ---------------- pass 1: bin edges into 512-node buckets ----------------
__launch_bounds__(256)
__global__ void k_bin(const int* __restrict__ src, const int* __restrict__ dst,
                      int E, int nbuck, int capB,
                      int* __restrict__ cursor, int* __restrict__ binned){
  __shared__ int cnt[128];
  __shared__ int segbase[128];
  const int tid = threadIdx.x;
  for (int t = tid; t < nbuck; t += 256) cnt[t] = 0;
  __syncthreads();
  const int e0 = blockIdx.x*4096 + tid;
  int pk[16], bk[16];
#pragma unroll
  for (int j = 0; j < 16; j++){
    int e = e0 + j*256;
    if (e < E){
      int d = dst[e], s = src[e];
      bk[j] = d >> 9;
      pk[j] = (s << 9) | (d & 511);
      atomicAdd(&cnt[bk[j]], 1);
    } else bk[j] = -1;
  }
  __syncthreads();
  for (int t = tid; t < nbuck; t += 256){
    int c = cnt[t];
    if (c > 0) segbase[t] = t*capB + atomicAdd(&cursor[t], c);
    cnt[t] = 0;
  }
  __syncthreads();
#pragma unroll
  for (int j = 0; j < 16; j++){
    if (bk[j] >= 0){
      int ord = atomicAdd(&cnt[bk[j]], 1);
      binned[segbase[bk[j]] + ord] = pk[j];
    }
  }
}

// ---------------- pass 2: per-bucket CSR, src-octile-ordered neighbor lists ----------------
// sd[n] = (csr_start, (true_deg << 16) | padded_deg)
__launch_bounds__(256)
__global__ void k_build(const int* __restrict__ binned, const int* __restrict__ cursor,
                        int N, int capB, int capC,
                        int2* __restrict__ sd, int* __restrict__ csr){
  __shared__ int deg2[512*8];
  __shared__ int lst2[512*8];
  __shared__ int cnt2[512*8];
  __shared__ int scn[256];
  const int b = blockIdx.x, tid = threadIdx.x;
  for (int t = tid; t < 512*8; t += 256){ deg2[t] = 0; cnt2[t] = 0; }
  __syncthreads();
  const int nE = cursor[b];
  const int gbase = b*capB;
  for (int i = tid; i < nE; i += 256){
    int v = binned[gbase + i];
    int o = v >> (9 + OSH);
    if (o > 7) o = 7;
    atomicAdd(&deg2[((v & 511) << 3) + o], 1);
  }
  __syncthreads();
  int d0 = 0, d1 = 0;
#pragma unroll
  for (int o = 0; o < 8; o++){ d0 += deg2[((2*tid) << 3) + o]; d1 += deg2[((2*tid+1) << 3) + o]; }
  const int p0 = (d0+7)&~7, p1 = (d1+7)&~7;
  scn[tid] = p0 + p1;
  __syncthreads();
#pragma unroll
  for (int off = 1; off < 256; off <<= 1){
    int add = (tid >= off) ? scn[tid-off] : 0;
    __syncthreads();
    scn[tid] += add;
    __syncthreads();
  }
  const int ex = scn[tid] - (p0 + p1);
  const int csrb = b*capC;
  {
    int off0 = ex;
#pragma unroll
    for (int o = 0; o < 8; o++){ lst2[((2*tid) << 3) + o] = off0; off0 += deg2[((2*tid) << 3) + o]; }
    int off1 = ex + p0;
#pragma unroll
    for (int o = 0; o < 8; o++){ lst2[((2*tid+1) << 3) + o] = off1; off1 += deg2[((2*tid+1) << 3) + o]; }
  }
  const int n0 = b*512 + 2*tid, n1 = n0 + 1;
  if (n0 < N) sd[n0] = make_int2(csrb + ex, (d0 << 16) | p0);
  if (n1 < N) sd[n1] = make_int2(csrb + ex + p0, (d1 << 16) | p1);
  __syncthreads();
  for (int i = tid; i < nE; i += 256){
    int v = binned[gbase + i];
    int dl = v & 511, s = v >> 9;
    int o = s >> OSH; if (o > 7) o = 7;
    int ord = atomicAdd(&cnt2[(dl << 3) + o], 1);
    csr[csrb + lst2[(dl << 3) + o] + ord] = s;
  }
  for (int j = d0; j < p0; j++) csr[csrb + ex + j] = N;
  for (int j = d1; j < p1; j++) csr[csrb + ex + p0 + j] = N;
}

// ---------------- fused layer kernel: out_l = (A x_l) W_l + deg*b, heads + SE(3) ----------
// 64 nodes/block, 512 threads (8 waves). Gather: wave w owns rows w*8..w*8+7, processed in
// PAIRS (two csr rows -> one wait; 16 X-row loads in flight instead of 8). MFMA: wave w does
// row-tile (w&3) x col-half (w>>2). Store + head GEMM + SE(3) as before.
__launch_bounds__(512)
__global__ void k_fused(const _Float16* __restrict__ Xin,     // (N+1) rows fp16
                        const _Float16* __restrict__ Wmain,   // 128x128 [col][k]
                        const _Float16* __restrict__ Whd,     // 16x128  [col][k]
                        const float* __restrict__ bias,       // bl[layer] (128)
                        const int* __restrict__ csr, const int2* __restrict__ sd,
                        _Float16* __restrict__ Out,           // (N+1) rows fp16
                        int N, int layer,
                        const float* __restrict__ bc, const float* __restrict__ bR,
                        const float* __restrict__ bt, const float* __restrict__ pos_in,
                        float* __restrict__ pos_o, float* __restrict__ R_o,
                        float* __restrict__ t_o){
  __shared__ __align__(16) _Float16 lg[64][136];   // gather tile, reused for out staging
  __shared__ __align__(16) float lheads[64*16];
  __shared__ float ldeg[64];

  const int tid  = threadIdx.x;
  const int wave = tid >> 6;
  const int lane = tid & 63;
  const int quad = lane >> 4;
  const int l16  = lane & 15;
  const int rbase0 = blockIdx.x*64;

  // ---- phase 1: paired-row gather-aggregate (wave w -> local rows w*8 .. w*8+7) ----
  {
    const int nbase = rbase0 + wave*8;
    int nn = nbase + (lane & 7);
    int2 sv = (nn < N) ? sd[nn] : make_int2(0, 0);
    const unsigned int* Xu = (const unsigned int*)Xin;
    for (int i = 0; i < 8; i += 2){
      int s0A = __builtin_amdgcn_readlane(sv.x, i);
      int dpA = __builtin_amdgcn_readlane(sv.y, i);
      int s0B = __builtin_amdgcn_readlane(sv.x, i+1);
      int dpB = __builtin_amdgcn_readlane(sv.y, i+1);
      int degA = dpA & 0xffff, degB = dpB & 0xffff;
      if (lane == 0){
        ldeg[wave*8 + i]     = (float)(dpA >> 16);
        ldeg[wave*8 + i + 1] = (float)(dpB >> 16);
      }
      float a0 = 0.f, a1 = 0.f, b0 = 0.f, b1 = 0.f;
      int maxd = degA > degB ? degA : degB;
      for (int base = 0; base < maxd; base += 64){
        int idxA = 0, idxB = 0;
        if (base < degA) idxA = csr[s0A + base + lane];   // coalesced: 64 edges
        if (base < degB) idxB = csr[s0B + base + lane];
        int mA = degA - base; mA = mA < 0 ? 0 : (mA > 64 ? 64 : mA);
        int mB = degB - base; mB = mB < 0 ? 0 : (mB > 64 ? 64 : mB);
        int mM = mA > mB ? mA : mB;
        for (int k = 0; k < mM; k += 8){
          unsigned int vA[8], vB[8];
          if (k < mA){
#pragma unroll
            for (int j = 0; j < 8; j++){
              int idx = __builtin_amdgcn_readlane(idxA, k + j);   // SGPR row index
              vA[j] = Xu[(size_t)idx*64 + lane];
            }
          }
          if (k < mB){
#pragma unroll
            for (int j = 0; j < 8; j++){
              int idx = __builtin_amdgcn_readlane(idxB, k + j);
              vB[j] = Xu[(size_t)idx*64 + lane];
            }
          }
          if (k < mA){
#pragma unroll
            for (int j = 0; j < 8; j++){
              float2 f = __half22float2(*(__half2*)&vA[j]);
              a0 += f.x; a1 += f.y;
            }
          }
          if (k < mB){
#pragma unroll
            for (int j = 0; j < 8; j++){
              float2 f = __half22float2(*(__half2*)&vB[j]);
              b0 += f.x; b1 += f.y;
            }
          }
        }
      }
      __half2 hoA = __floats2half2_rn(a0, a1);
      ((unsigned int*)&lg[wave*8 + i][0])[lane] = *(unsigned int*)&hoA;
      __half2 hoB = __floats2half2_rn(b0, b1);
      ((unsigned int*)&lg[wave*8 + i + 1][0])[lane] = *(unsigned int*)&hoB;
    }
  }
  __syncthreads();

  // ---- phase 2: MFMA GEMM. wave w: row-tile (w&3), col-half (w>>2) ----
  const int rt4 = wave & 3;         // rows rt4*16 .. rt4*16+15
  const int cq  = wave >> 2;        // cols cq*64 .. cq*64+63 (4 col-tiles)
  half8 af[4];
#pragma unroll
  for (int kc = 0; kc < 4; kc++)
    af[kc] = *(const half8*)&lg[rt4*16 + l16][kc*32 + quad*8];
  __syncthreads();   // all lg reads done before out staging overwrites it

  floatx4 acc[4] = {};
#pragma unroll
  for (int kc = 0; kc < 4; kc++)
#pragma unroll
    for (int ct = 0; ct < 4; ct++){
      half8 bf = *(const half8*)(Wmain + (size_t)((cq*4 + ct)*16 + l16)*128 + kc*32 + quad*8);
      acc[ct] = __builtin_amdgcn_mfma_f32_16x16x32_f16(af[kc], bf, acc[ct], 0, 0, 0);
    }

  // ---- stage out to LDS (deg-scaled bias: reference sums (x W + b) over neighbors) ----
  {
    float dgv[4];
#pragma unroll
    for (int reg = 0; reg < 4; reg++)
      dgv[reg] = ldeg[rt4*16 + quad*4 + reg];
#pragma unroll
    for (int ct = 0; ct < 4; ct++){
      int col = (cq*4 + ct)*16 + l16;
      float b = bias[col];
#pragma unroll
      for (int reg = 0; reg < 4; reg++){
        int rl = rt4*16 + quad*4 + reg;
        lg[rl][col] = (_Float16)(acc[ct][reg] + b*dgv[reg]);
      }
    }
  }
  __syncthreads();

  // ---- phase 3a: coalesced global store (half8 chunks), zero row N for csr padding ----
#pragma unroll
  for (int i = 0; i < 2; i++){
    int idx8 = i*512 + tid;            // 1024 half8 chunks
    int row = idx8 >> 4, c8 = idx8 & 15;
    int gr = rbase0 + row;
    if (gr < N){
      *(half8*)(Out + (size_t)gr*128 + c8*8) = *(const half8*)&lg[row][c8*8];
    } else if (gr == N){
      half8 z = {};
      *(half8*)(Out + (size_t)gr*128 + c8*8) = z;
    }
  }

  // ---- phase 3b: head GEMM out_l @ Whd (waves 0-3 -> row-tiles 0-3) ----
  if (wave < 4){
    floatx4 hacc = {};
#pragma unroll
    for (int kc = 0; kc < 4; kc++){
      half8 ha = *(const half8*)&lg[wave*16 + l16][kc*32 + quad*8];
      half8 bf = *(const half8*)(Whd + (size_t)l16*128 + kc*32 + quad*8);
      hacc = __builtin_amdgcn_mfma_f32_16x16x32_f16(ha, bf, hacc, 0, 0, 0);
    }
#pragma unroll
    for (int reg = 0; reg < 4; reg++)
      lheads[(wave*16 + quad*4 + reg)*16 + l16] = hacc[reg];
  }
  __syncthreads();

  // ---- phase 4: SE(3) epilogue for this layer ----
  if (tid < 64){
    int n = rbase0 + tid;
    if (n < N){
      float ds[13];
#pragma unroll
      for (int c = 0; c < 13; c++) ds[c] = lheads[tid*16 + c];
      se3_node_ds(n, ds, bc, bR, bt, pos_in, pos_o, R_o, t_o, layer);
    }
  }
}

// ---------------- final GEMM: z = out_2 @ Wf + bf (fp32 out, no gather/heads) ----------
__launch_bounds__(256)
__global__ void k_final(const _Float16* __restrict__ X, const _Float16* __restrict__ Wmain,
                        const float* __restrict__ bias, float* __restrict__ Z, int M){
  __shared__ __align__(16) float lf[64][128];
  const int tid  = threadIdx.x;
  const int wave = tid >> 6;
  const int lane = tid & 63;
  const int quad = lane >> 4;
  const int l16  = lane & 15;
  const int rbase0 = blockIdx.x*64;
  const int rbase  = rbase0 + (wave & 1)*32;
  const int cthi = wave >> 1;

  half8 af[4][2];
#pragma unroll
  for (int kc = 0; kc < 4; kc++)
#pragma unroll
    for (int rt = 0; rt < 2; rt++){
      int r = rbase + rt*16 + l16;
      r = (r < M) ? r : (M - 1);
      af[kc][rt] = *(const half8*)(X + (size_t)r*128 + kc*32 + quad*8);
    }

  floatx4 acc[2][4] = {};
#pragma unroll
  for (int kc = 0; kc < 4; kc++)
#pragma unroll
    for (int ct = 0; ct < 4; ct++){
      half8 bf = *(const half8*)(Wmain + (size_t)((cthi*4 + ct)*16 + l16)*128 + kc*32 + quad*8);
      acc[0][ct] = __builtin_amdgcn_mfma_f32_16x16x32_f16(af[kc][0], bf, acc[0][ct], 0, 0, 0);
      acc[1][ct] = __builtin_amdgcn_mfma_f32_16x16x32_f16(af[kc][1], bf, acc[1][ct], 0, 0, 0);
    }

#pragma unroll
  for (int rt = 0; rt < 2; rt++)
#pragma unroll
    for (int ct = 0; ct < 4; ct++){
      int col = (cthi*4 + ct)*16 + l16;
      float b = bias[col];
#pragma unroll
      for (int reg = 0; reg < 4; reg++){
        int rl = (wave & 1)*32 + rt*16 + quad*4 + reg;
        lf[rl][col] = acc[rt][ct][reg] + b;
      }
    }
  __syncthreads();

#pragma unroll
  for (int i = 0; i < 8; i++){
    int idx4 = i*256 + tid;            // 2048 float4 chunks
    int row = idx4 >> 5, c4 = idx4 & 31;
    int gr = rbase0 + row;
    if (gr < M)
      *(float4*)(Z + (size_t)gr*128 + c4*4) = *(const float4*)&lf[row][c4*4];
  }
}

extern "C" void kernel_launch(void* const* d_in, const int* in_sizes, int n_in,
                              void* d_out, int out_size, void* d_ws, size_t ws_size,
                              hipStream_t stream){
  const float* x0  = (const float*)d_in[0];
  const float* pos = (const float*)d_in[1];
  const int*   ei  = (const int*)d_in[2];
  const float* Wl  = (const float*)d_in[3];
  const float* bl  = (const float*)d_in[4];
  const float* Wc  = (const float*)d_in[5];
  const float* bc  = (const float*)d_in[6];
  const float* WR  = (const float*)d_in[7];
  const float* bR  = (const float*)d_in[8];
  const float* Wt  = (const float*)d_in[9];
  const float* bt  = (const float*)d_in[10];
  const float* Wf  = (const float*)d_in[11];
  const float* bf  = (const float*)d_in[12];

  const int N = in_sizes[0] / 128;
  const int E = in_sizes[2] / 2;
  const int* srcp = ei;
  const int* dstp = ei + E;

  float* z_out = (float*)d_out;
  float* pos_o = z_out + (size_t)N*128;
  float* R_o   = pos_o + (size_t)N*3;
  float* t_o   = R_o   + (size_t)N*9;

  const int nbuck = (N + 511) >> 9;
  const int capB  = (((E + nbuck - 1)/nbuck)*5/4 + 256 + 63) & ~63;
  const int capC  = capB + 512*7;

  char* ws = (char*)d_ws;
  size_t off = 0;
  auto alloc = [&](size_t bytes)->char*{
    char* p = ws + off; off += (bytes + 511) & ~(size_t)511; return p;
  };
  _Float16* bufA = (_Float16*)alloc((size_t)(N+1)*128*2);   // x16 / out1
  _Float16* bufB = (_Float16*)alloc((size_t)(N+1)*128*2);   // out0 / out2
  _Float16* wTx  = (_Float16*)alloc((size_t)4*128*128*2);
  _Float16* wHd  = (_Float16*)alloc((size_t)3*16*128*2);
  int2*  sd     = (int2*) alloc((size_t)N*8);
  int*   cursor = (int*)  alloc((size_t)nbuck*4);
  int*   binned = (int*)  alloc((size_t)nbuck*capB*4);
  int*   csr    = (int*)  alloc((size_t)nbuck*capC*4);

  const int prep_total = 4*128*128 + 3*16*128;
  k_prep_w<<<dim3((prep_total + 255)/256), dim3(256), 0, stream>>>(
      Wl, Wf, Wc, WR, Wt, wTx, wHd, cursor, nbuck);
  k_bin   <<<dim3((E + 4095)/4096), dim3(256), 0, stream>>>(srcp, dstp, E, nbuck, capB, cursor, binned);
  k_build <<<dim3(nbuck), dim3(256), 0, stream>>>(binned, cursor, N, capB, capC, sd, csr);
  k_cvt   <<<dim3(((N+1)*16 + 255)/256), dim3(256), 0, stream>>>(x0, bufA, N);

  const int fused_blocks = (N + 64) >> 6;   // 64 rows/block; covers zero-pad row N
  const int final_blocks = (N + 63) >> 6;

  const _Float16* xin = bufA;
  _Float16* xout = bufB;
  for (int layer = 0; layer < 3; layer++){
    k_fused<<<dim3(fused_blocks), dim3(512), 0, stream>>>(
        xin, wTx + (size_t)layer*16384, wHd + (size_t)layer*2048, bl + (size_t)layer*128,
        csr, sd, xout, N, layer,
        bc + layer, bR + (size_t)layer*9, bt + (size_t)layer*3,
        pos, pos_o, R_o, t_o);
    const _Float16* tmp = xin; xin = xout; xout = (_Float16*)tmp;
  }
  // after 3 swaps: xin = out_2
  k_final<<<dim3(final_blocks), dim3(256), 0, stream>>>(
      xin, wTx + (size_t)3*16384, bf, z_out, N);
}

// Round 4
// 273.100 us; speedup vs baseline: 1.1269x; 1.0796x over previous
//
#include <hip/hip_runtime.h>
#include <hip/hip_fp16.h>

typedef _Float16 half8 __attribute__((ext_vector_type(8)));
typedef float floatx4 __attribute__((ext_vector_type(4)));

#define OSH 13            // src-octile shift for csr ordering (locality in gather)

// ---------------- QR: 3x3 Householder, LAPACK sgeqrf/sorgqr convention ----------------
__device__ inline void qr3_q(const double A[3][3], double Q[3][3]){
  double a[3][3];
#pragma unroll
  for (int r = 0; r < 3; r++)
#pragma unroll
    for (int c = 0; c < 3; c++) a[r][c] = A[r][c];

  double v1[3] = {1.0, 0.0, 0.0};
  double tau1 = 0.0;
  {
    double xn2 = a[1][0]*a[1][0] + a[2][0]*a[2][0];
    if (xn2 != 0.0){
      double alpha = a[0][0];
      double beta = -copysign(sqrt(alpha*alpha + xn2), alpha);
      tau1 = (beta - alpha) / beta;
      double inv = 1.0 / (alpha - beta);
      v1[1] = a[1][0] * inv;
      v1[2] = a[2][0] * inv;
#pragma unroll
      for (int c = 1; c < 3; c++){
        double w = a[0][c] + v1[1]*a[1][c] + v1[2]*a[2][c];
        double tw = tau1 * w;
        a[0][c] -= tw;
        a[1][c] -= tw * v1[1];
        a[2][c] -= tw * v1[2];
      }
    }
  }
  double tau2 = 0.0, v2 = 0.0;
  {
    double x2 = a[2][1];
    if (x2 != 0.0){
      double alpha = a[1][1];
      double beta = -copysign(sqrt(alpha*alpha + x2*x2), alpha);
      tau2 = (beta - alpha) / beta;
      v2 = x2 / (alpha - beta);
    }
  }
  double M[3][3] = {{1.0, 0.0, 0.0},
                    {0.0, 1.0 - tau2, -tau2*v2},
                    {0.0, -tau2*v2, 1.0 - tau2*v2*v2}};
#pragma unroll
  for (int c = 0; c < 3; c++){
    double w = v1[0]*M[0][c] + v1[1]*M[1][c] + v1[2]*M[2][c];
#pragma unroll
    for (int r = 0; r < 3; r++)
      Q[r][c] = M[r][c] - tau1 * v1[r] * w;
  }
}

// ---------------- SE(3) per-node epilogue from a local ds[13] ----------------
__device__ inline void se3_node_ds(int n, const float ds[13],
                                   const float* __restrict__ bc, const float* __restrict__ bR,
                                   const float* __restrict__ bt, const float* __restrict__ pos_in,
                                   float* __restrict__ pos_o, float* __restrict__ R_o,
                                   float* __restrict__ t_o, int layer){
  double A[3][3], Q[3][3];
#pragma unroll
  for (int r = 0; r < 3; r++)
#pragma unroll
    for (int c = 0; c < 3; c++)
      A[r][c] = (double)ds[1 + r*3 + c] + (double)bR[r*3 + c];
  qr3_q(A, Q);

  double pd = (double)ds[0] + (double)bc[0];
#pragma unroll
  for (int c = 0; c < 3; c++){
    double base = (layer == 0) ? (double)pos_in[n*3 + c] : (double)pos_o[n*3 + c];
    pos_o[n*3 + c] = (float)(base + pd);
  }

  if (layer == 0){
#pragma unroll
    for (int r = 0; r < 3; r++)
#pragma unroll
      for (int c = 0; c < 3; c++)
        R_o[n*9 + r*3 + c] = (float)Q[r][c];
  } else {
    double Rold[3][3];
#pragma unroll
    for (int r = 0; r < 3; r++)
#pragma unroll
      for (int c = 0; c < 3; c++)
        Rold[r][c] = (double)R_o[n*9 + r*3 + c];
#pragma unroll
    for (int r = 0; r < 3; r++)
#pragma unroll
      for (int c = 0; c < 3; c++){
        double s = Q[r][0]*Rold[0][c] + Q[r][1]*Rold[1][c] + Q[r][2]*Rold[2][c];
        R_o[n*9 + r*3 + c] = (float)s;
      }
  }
#pragma unroll
  for (int c = 0; c < 3; c++){
    double base = (layer == 0) ? 0.0 : (double)t_o[n*3 + c];
    t_o[n*3 + c] = (float)(base + (double)ds[10 + c] + (double)bt[c]);
  }
}

// ---------------- merged pre-kernel: x fp32->fp16 cvt + weight prep + cursor init ------
// blocks [0, cvtB): cvt (row N zeroed). blocks [cvtB, ...): weight prep.
// wTx: 4 slots x 128 cols x 128 k (main W, B-frag layout [col][k])
// wHd: 3 slots x 16 cols x 128 k (head W of layer l in slot l; cols 13-15 zero)
__launch_bounds__(256)
__global__ void k_pre(const float* __restrict__ x, _Float16* __restrict__ o, int N,
                      const float* __restrict__ Wl, const float* __restrict__ Wf,
                      const float* __restrict__ Wc, const float* __restrict__ WR,
                      const float* __restrict__ Wt, _Float16* __restrict__ wTx,
                      _Float16* __restrict__ wHd,
                      int* __restrict__ cursor, int nbuck, int cvtB){
  const int b = blockIdx.x;
  if (b < cvtB){
    int c = b*256 + threadIdx.x;       // half8 chunk id
    if (c >= (N+1)*16) return;
    int n = c >> 4;
    half8 h = {};
    if (n < N){
      const float* p = x + (size_t)c*8;
      float4 f0 = *(const float4*)p;
      float4 f1 = *(const float4*)(p + 4);
      h[0]=(_Float16)f0.x; h[1]=(_Float16)f0.y; h[2]=(_Float16)f0.z; h[3]=(_Float16)f0.w;
      h[4]=(_Float16)f1.x; h[5]=(_Float16)f1.y; h[6]=(_Float16)f1.z; h[7]=(_Float16)f1.w;
    }
    *(half8*)(o + (size_t)c*8) = h;
    return;
  }
  if (b == cvtB && threadIdx.x < nbuck) cursor[threadIdx.x] = 0;
  int t = (b - cvtB)*256 + threadIdx.x;
  if (t < 4*128*128){
    int l = t >> 14;
    int n = (t >> 7) & 127;
    int k = t & 127;
    const float* W = (l < 3) ? (Wl + (size_t)l*16384) : Wf;
    wTx[t] = (_Float16)W[k*128 + n];
  } else if (t < 4*128*128 + 3*16*128){
    int u = t - 4*128*128;
    int l = u >> 11;              // 16*128 = 2048 per slot
    int r = u & 2047;
    int n = r >> 7;
    int k = r & 127;
    float v = 0.f;
    if (n == 0)      v = Wc[(size_t)l*128 + k];
    else if (n < 10) v = WR[(size_t)l*1152 + k*9 + (n-1)];
    else if (n < 13) v = Wt[(size_t)l*384 + k*3 + (n-10)];
    wHd[u] = (_Float16)v;
  }
}

// ---------------- pass 1: bin edges into 512-node buckets ----------------
__launch_bounds__(256)
__global__ void k_bin(const int* __restrict__ src, const int* __restrict__ dst,
                      int E, int nbuck, int capB,
                      int* __restrict__ cursor, int* __restrict__ binned){
  __shared__ int cnt[128];
  __shared__ int segbase[128];
  const int tid = threadIdx.x;
  for (int t = tid; t < nbuck; t += 256) cnt[t] = 0;
  __syncthreads();
  const int e0 = blockIdx.x*4096 + tid;
  int pk[16], bk[16];
#pragma unroll
  for (int j = 0; j < 16; j++){
    int e = e0 + j*256;
    if (e < E){
      int d = dst[e], s = src[e];
      bk[j] = d >> 9;
      pk[j] = (s << 9) | (d & 511);
      atomicAdd(&cnt[bk[j]], 1);
    } else bk[j] = -1;
  }
  __syncthreads();
  for (int t = tid; t < nbuck; t += 256){
    int c = cnt[t];
    if (c > 0) segbase[t] = t*capB + atomicAdd(&cursor[t], c);
    cnt[t] = 0;
  }
  __syncthreads();
#pragma unroll
  for (int j = 0; j < 16; j++){
    if (bk[j] >= 0){
      int ord = atomicAdd(&cnt[bk[j]], 1);
      binned[segbase[bk[j]] + ord] = pk[j];
    }
  }
}

// ---------------- pass 2: per-bucket CSR, src-octile-ordered neighbor lists ----------------
// sd[n] = (csr_start, (true_deg << 16) | padded_deg)
__launch_bounds__(256)
__global__ void k_build(const int* __restrict__ binned, const int* __restrict__ cursor,
                        int N, int capB, int capC,
                        int2* __restrict__ sd, int* __restrict__ csr){
  __shared__ int deg2[512*8];
  __shared__ int lst2[512*8];
  __shared__ int cnt2[512*8];
  __shared__ int scn[256];
  const int b = blockIdx.x, tid = threadIdx.x;
  for (int t = tid; t < 512*8; t += 256){ deg2[t] = 0; cnt2[t] = 0; }
  __syncthreads();
  const int nE = cursor[b];
  const int gbase = b*capB;
  for (int i = tid; i < nE; i += 256){
    int v = binned[gbase + i];
    int o = v >> (9 + OSH);
    if (o > 7) o = 7;
    atomicAdd(&deg2[((v & 511) << 3) + o], 1);
  }
  __syncthreads();
  int d0 = 0, d1 = 0;
#pragma unroll
  for (int o = 0; o < 8; o++){ d0 += deg2[((2*tid) << 3) + o]; d1 += deg2[((2*tid+1) << 3) + o]; }
  const int p0 = (d0+7)&~7, p1 = (d1+7)&~7;
  scn[tid] = p0 + p1;
  __syncthreads();
#pragma unroll
  for (int off = 1; off < 256; off <<= 1){
    int add = (tid >= off) ? scn[tid-off] : 0;
    __syncthreads();
    scn[tid] += add;
    __syncthreads();
  }
  const int ex = scn[tid] - (p0 + p1);
  const int csrb = b*capC;
  {
    int off0 = ex;
#pragma unroll
    for (int o = 0; o < 8; o++){ lst2[((2*tid) << 3) + o] = off0; off0 += deg2[((2*tid) << 3) + o]; }
    int off1 = ex + p0;
#pragma unroll
    for (int o = 0; o < 8; o++){ lst2[((2*tid+1) << 3) + o] = off1; off1 += deg2[((2*tid+1) << 3) + o]; }
  }
  const int n0 = b*512 + 2*tid, n1 = n0 + 1;
  if (n0 < N) sd[n0] = make_int2(csrb + ex, (d0 << 16) | p0);
  if (n1 < N) sd[n1] = make_int2(csrb + ex + p0, (d1 << 16) | p1);
  __syncthreads();
  for (int i = tid; i < nE; i += 256){
    int v = binned[gbase + i];
    int dl = v & 511, s = v >> 9;
    int o = s >> OSH; if (o > 7) o = 7;
    int ord = atomicAdd(&cnt2[(dl << 3) + o], 1);
    csr[csrb + lst2[(dl << 3) + o] + ord] = s;
  }
  for (int j = d0; j < p0; j++) csr[csrb + ex + j] = N;
  for (int j = d1; j < p1; j++) csr[csrb + ex + p0 + j] = N;
}

// ---------------- fused layer kernel: out_l = (A x_l) W_l + deg*b, heads + SE(3) ----------
// Per block: 64 nodes, 256 threads (R1 geometry — best measured).
// Phase 1: each wave gather-aggregates 16 rows of A*x into LDS (fp16).
// Phase 2: 64x128x128 MFMA GEMM (A from LDS, B=wTx), deg-scaled bias, stage out to LDS.
// Phase 3: layers 0/1: coalesced global store of out (+ zero row N); layer 2 (Wfin!=null):
//          z = out @ Wf + bf computed in-block, fp32 stores direct (out never hits global).
// Phase 3b: 64x16x128 head MFMA from LDS. Phase 4: SE(3) epilogue.
__launch_bounds__(256)
__global__ void k_fused(const _Float16* __restrict__ Xin,     // (N+1) rows fp16
                        const _Float16* __restrict__ Wmain,   // 128x128 [col][k]
                        const _Float16* __restrict__ Whd,     // 16x128  [col][k]
                        const float* __restrict__ bias,       // bl[layer] (128)
                        const int* __restrict__ csr, const int2* __restrict__ sd,
                        _Float16* __restrict__ Out,           // (N+1) rows fp16
                        int N, int layer,
                        const float* __restrict__ bc, const float* __restrict__ bR,
                        const float* __restrict__ bt, const float* __restrict__ pos_in,
                        float* __restrict__ pos_o, float* __restrict__ R_o,
                        float* __restrict__ t_o,
                        const _Float16* __restrict__ Wfin,    // final-layer: Wf (else null)
                        const float* __restrict__ bfin,       // final-layer: bf
                        float* __restrict__ Zout){            // final-layer: z (fp32)
  __shared__ __align__(16) _Float16 lg[64][136];   // gather tile, reused for out staging
  __shared__ __align__(16) float lheads[64*16];
  __shared__ float ldeg[64];

  const int tid  = threadIdx.x;
  const int wave = tid >> 6;
  const int lane = tid & 63;
  const int quad = lane >> 4;
  const int l16  = lane & 15;
  const int rbase0 = blockIdx.x*64;

  // ---- phase 1: gather-aggregate (wave w -> local rows w*16 .. w*16+15) ----
  {
    const int nbase = rbase0 + wave*16;
    int nn = nbase + (lane & 15);
    int2 sv = (nn < N) ? sd[nn] : make_int2(0, 0);
    const unsigned int* Xu = (const unsigned int*)Xin;
    for (int i = 0; i < 16; i++){
      int s0    = __builtin_amdgcn_readlane(sv.x, i);
      int dpack = __builtin_amdgcn_readlane(sv.y, i);
      int degp  = dpack & 0xffff;
      if (lane == 0) ldeg[wave*16 + i] = (float)(dpack >> 16);
      float acc0 = 0.f, acc1 = 0.f;
      for (int base = 0; base < degp; base += 64){
        int myidx = csr[s0 + base + lane];          // one coalesced load covers 64 edges
        int m = degp - base; m = (m < 64) ? m : 64; // multiple of 8
        for (int k = 0; k < m; k += 8){
          unsigned int v[8];
#pragma unroll
          for (int j = 0; j < 8; j++){
            int idx = __builtin_amdgcn_readlane(myidx, k + j);   // SGPR row index
            v[j] = Xu[(size_t)idx*64 + lane];
          }
#pragma unroll
          for (int j = 0; j < 8; j++){
            float2 f = __half22float2(*(__half2*)&v[j]);
            acc0 += f.x; acc1 += f.y;
          }
        }
      }
      __half2 ho = __floats2half2_rn(acc0, acc1);
      ((unsigned int*)&lg[wave*16 + i][0])[lane] = *(unsigned int*)&ho;
    }
  }
  __syncthreads();

  // ---- phase 2: MFMA GEMM. waves 0,1: cols 0-63; waves 2,3: cols 64-127 ----
  const int cthi = wave >> 1;
  half8 af[4][2];
#pragma unroll
  for (int kc = 0; kc < 4; kc++)
#pragma unroll
    for (int rt = 0; rt < 2; rt++){
      int rl = (wave & 1)*32 + rt*16 + l16;
      af[kc][rt] = *(const half8*)&lg[rl][kc*32 + quad*8];
    }
  __syncthreads();   // all lg reads done before out staging overwrites it

  floatx4 acc[2][4] = {};
#pragma unroll
  for (int kc = 0; kc < 4; kc++)
#pragma unroll
    for (int ct = 0; ct < 4; ct++){
      half8 bf = *(const half8*)(Wmain + (size_t)((cthi*4 + ct)*16 + l16)*128 + kc*32 + quad*8);
      acc[0][ct] = __builtin_amdgcn_mfma_f32_16x16x32_f16(af[kc][0], bf, acc[0][ct], 0, 0, 0);
      acc[1][ct] = __builtin_amdgcn_mfma_f32_16x16x32_f16(af[kc][1], bf, acc[1][ct], 0, 0, 0);
    }

  // ---- stage out to LDS (deg-scaled bias: reference sums (x W + b) over neighbors) ----
#pragma unroll
  for (int rt = 0; rt < 2; rt++){
    float dgv[4];
#pragma unroll
    for (int reg = 0; reg < 4; reg++)
      dgv[reg] = ldeg[(wave & 1)*32 + rt*16 + quad*4 + reg];
#pragma unroll
    for (int ct = 0; ct < 4; ct++){
      int col = (cthi*4 + ct)*16 + l16;
      float b = bias[col];
#pragma unroll
      for (int reg = 0; reg < 4; reg++){
        int rl = (wave & 1)*32 + rt*16 + quad*4 + reg;
        lg[rl][col] = (_Float16)(acc[ct == 0 ? rt : rt][ct][reg] + b*dgv[reg]);
      }
    }
  }
  __syncthreads();

  if (Wfin == nullptr){
    // ---- phase 3a: coalesced global store (half8 chunks), zero row N for csr padding ----
#pragma unroll
    for (int i = 0; i < 4; i++){
      int idx8 = i*256 + tid;            // 1024 half8 chunks
      int row = idx8 >> 4, c8 = idx8 & 15;
      int gr = rbase0 + row;
      if (gr < N){
        *(half8*)(Out + (size_t)gr*128 + c8*8) = *(const half8*)&lg[row][c8*8];
      } else if (gr == N){
        half8 z = {};
        *(half8*)(Out + (size_t)gr*128 + c8*8) = z;
      }
    }
  } else {
    // ---- phase 3a': fused final GEMM  z = out @ Wf + bf, direct fp32 store ----
    half8 zf[4][2];
#pragma unroll
    for (int kc = 0; kc < 4; kc++)
#pragma unroll
      for (int rt = 0; rt < 2; rt++){
        int rl = (wave & 1)*32 + rt*16 + l16;
        zf[kc][rt] = *(const half8*)&lg[rl][kc*32 + quad*8];
      }
    floatx4 zacc[2][4] = {};
#pragma unroll
    for (int kc = 0; kc < 4; kc++)
#pragma unroll
      for (int ct = 0; ct < 4; ct++){
        half8 bf = *(const half8*)(Wfin + (size_t)((cthi*4 + ct)*16 + l16)*128 + kc*32 + quad*8);
        zacc[0][ct] = __builtin_amdgcn_mfma_f32_16x16x32_f16(zf[kc][0], bf, zacc[0][ct], 0, 0, 0);
        zacc[1][ct] = __builtin_amdgcn_mfma_f32_16x16x32_f16(zf[kc][1], bf, zacc[1][ct], 0, 0, 0);
      }
#pragma unroll
    for (int rt = 0; rt < 2; rt++)
#pragma unroll
      for (int ct = 0; ct < 4; ct++){
        int col = (cthi*4 + ct)*16 + l16;
        float b = bfin[col];
#pragma unroll
        for (int reg = 0; reg < 4; reg++){
          int gr = rbase0 + (wave & 1)*32 + rt*16 + quad*4 + reg;
          if (gr < N) Zout[(size_t)gr*128 + col] = zacc[rt][ct][reg] + b;
        }
      }
  }

  // ---- phase 3b: head GEMM out_l @ Whd (wave w -> row-tile w) ----
  {
    floatx4 hacc = {};
#pragma unroll
    for (int kc = 0; kc < 4; kc++){
      half8 ha = *(const half8*)&lg[wave*16 + l16][kc*32 + quad*8];
      half8 bf = *(const half8*)(Whd + (size_t)l16*128 + kc*32 + quad*8);
      hacc = __builtin_amdgcn_mfma_f32_16x16x32_f16(ha, bf, hacc, 0, 0, 0);
    }
#pragma unroll
    for (int reg = 0; reg < 4; reg++)
      lheads[(wave*16 + quad*4 + reg)*16 + l16] = hacc[reg];
  }
  __syncthreads();

  // ---- phase 4: SE(3) epilogue for this layer ----
  if (tid < 64){
    int n = rbase0 + tid;
    if (n < N){
      float ds[13];
#pragma unroll
      for (int c = 0; c < 13; c++) ds[c] = lheads[tid*16 + c];
      se3_node_ds(n, ds, bc, bR, bt, pos_in, pos_o, R_o, t_o, layer);
    }
  }
}

extern "C" void kernel_launch(void* const* d_in, const int* in_sizes, int n_in,
                              void* d_out, int out_size, void* d_ws, size_t ws_size,
                              hipStream_t stream){
  const float* x0  = (const float*)d_in[0];
  const float* pos = (const float*)d_in[1];
  const int*   ei  = (const int*)d_in[2];
  const float* Wl  = (const float*)d_in[3];
  const float* bl  = (const float*)d_in[4];
  const float* Wc  = (const float*)d_in[5];
  const float* bc  = (const float*)d_in[6];
  const float* WR  = (const float*)d_in[7];
  const float* bR  = (const float*)d_in[8];
  const float* Wt  = (const float*)d_in[9];
  const float* bt  = (const float*)d_in[10];
  const float* Wf  = (const float*)d_in[11];
  const float* bf  = (const float*)d_in[12];

  const int N = in_sizes[0] / 128;
  const int E = in_sizes[2] / 2;
  const int* srcp = ei;
  const int* dstp = ei + E;

  float* z_out = (float*)d_out;
  float* pos_o = z_out + (size_t)N*128;
  float* R_o   = pos_o + (size_t)N*3;
  float* t_o   = R_o   + (size_t)N*9;

  const int nbuck = (N + 511) >> 9;
  const int capB  = (((E + nbuck - 1)/nbuck)*5/4 + 256 + 63) & ~63;
  const int capC  = capB + 512*7;

  char* ws = (char*)d_ws;
  size_t off = 0;
  auto alloc = [&](size_t bytes)->char*{
    char* p = ws + off; off += (bytes + 511) & ~(size_t)511; return p;
  };
  _Float16* bufA = (_Float16*)alloc((size_t)(N+1)*128*2);   // x16 / out1
  _Float16* bufB = (_Float16*)alloc((size_t)(N+1)*128*2);   // out0 (out2 never stored)
  _Float16* wTx  = (_Float16*)alloc((size_t)4*128*128*2);
  _Float16* wHd  = (_Float16*)alloc((size_t)3*16*128*2);
  int2*  sd     = (int2*) alloc((size_t)N*8);
  int*   cursor = (int*)  alloc((size_t)nbuck*4);
  int*   binned = (int*)  alloc((size_t)nbuck*capB*4);
  int*   csr    = (int*)  alloc((size_t)nbuck*capC*4);

  const int cvtB = ((N+1)*16 + 255)/256;
  const int prep_total = 4*128*128 + 3*16*128;
  const int prepB = (prep_total + 255)/256;
  k_pre<<<dim3(cvtB + prepB), dim3(256), 0, stream>>>(
      x0, bufA, N, Wl, Wf, Wc, WR, Wt, wTx, wHd, cursor, nbuck, cvtB);
  k_bin   <<<dim3((E + 4095)/4096), dim3(256), 0, stream>>>(srcp, dstp, E, nbuck, capB, cursor, binned);
  k_build <<<dim3(nbuck), dim3(256), 0, stream>>>(binned, cursor, N, capB, capC, sd, csr);

  const int fused_blocks = (N + 64) >> 6;   // 64 rows/block; covers zero-pad row N

  const _Float16* xin = bufA;
  _Float16* xout = bufB;
  for (int layer = 0; layer < 3; layer++){
    const bool fin = (layer == 2);
    k_fused<<<dim3(fused_blocks), dim3(256), 0, stream>>>(
        xin, wTx + (size_t)layer*16384, wHd + (size_t)layer*2048, bl + (size_t)layer*128,
        csr, sd, xout, N, layer,
        bc + layer, bR + (size_t)layer*9, bt + (size_t)layer*3,
        pos, pos_o, R_o, t_o,
        fin ? (wTx + (size_t)3*16384) : nullptr,
        fin ? bf : nullptr,
        fin ? z_out : nullptr);
    const _Float16* tmp = xin; xin = xout; xout = (_Float16*)tmp;
  }
}